// Round 11
// baseline (1366.920 us; speedup 1.0000x reference)
//
#include <hip/hip_runtime.h>

// ---------- helpers ----------
typedef __attribute__((ext_vector_type(8))) short short8;
typedef __attribute__((ext_vector_type(4))) float f32x4;
typedef __attribute__((ext_vector_type(2))) float f32x2;

#if __has_builtin(__builtin_elementwise_fma)
#define PKFMA(a, b, c) __builtin_elementwise_fma(a, b, c)
#else
static __device__ __forceinline__ f32x2 PKFMA(f32x2 a, f32x2 b, f32x2 c) {
    f32x2 d; d[0] = fmaf(a[0], b[0], c[0]); d[1] = fmaf(a[1], b[1], c[1]);
    return d;
}
#endif

__device__ __forceinline__ unsigned short f2bf(float f) {
    unsigned int u = __float_as_uint(f);
    unsigned int r = (u + 0x7FFFu + ((u >> 16) & 1u)) >> 16;   // RNE
    return (unsigned short)r;
}

__device__ __forceinline__ void gload16(const void* g, void* l) {
    __builtin_amdgcn_global_load_lds(
        (const __attribute__((address_space(1))) unsigned int*)g,
        (__attribute__((address_space(3))) unsigned int*)l,
        16, 0, 0);
}

// ---------- Kernel 0: W1[2048][512] -> W1Tt[hc][512][128] (per-hc k-major tiles)
__global__ __launch_bounds__(256) void k_tw(const float* __restrict__ W1,
                                            float* __restrict__ W1Tt) {
    const int tx = threadIdx.x & 31, ty = threadIdx.x >> 5;   // 32 x 8
    const int k0 = blockIdx.x * 32, j0 = blockIdx.y * 32, hc = blockIdx.z;
    __shared__ float t[32][33];
#pragma unroll
    for (int i = 0; i < 4; ++i)
        t[ty + i * 8][tx] = W1[(size_t)(hc * 128 + j0 + ty + i * 8) * 512 + k0 + tx];
    __syncthreads();
#pragma unroll
    for (int i = 0; i < 4; ++i)
        W1Tt[(size_t)hc * 65536 + (size_t)(k0 + ty + i * 8) * 128 + j0 + tx] =
            t[tx][ty + i * 8];
}

// ---------- Kernel 1: fused FC1 (fp32 GEMM, fp64-chunk accum) + LIF scan ----------
// grid (32 h-chunks of 64, 256 batches), 256 threads. Tile 128s x 64h, K=512,
// BK=32. Round-11 changes (both bitwise-identical numerics):
//  - A (x) reads: global->registers (x is [s][k], natural float4 per k4; L1-hot
//    after first k4). Removes 64/96 LDS insts per tile (round-10 was
//    LDS-issue-bound: 96 b128 x 12cyc ~= 983us ~= 1039us wall).
//  - pk-FMA: f32x2 acc + elementwise_fma -> v_pk_fma_f32, 2 IEEE FMAs/inst,
//    per-element chain order unchanged.
// B stays LDS-staged (broadcast reuse), double-buffered, gload16 DMA.
// fp64 flush every 32 k as always. No min-waves launch_bounds (round-2 spill).
__global__ __launch_bounds__(256) void k_fc1_scan(
    const float* __restrict__ x,      // [256][128][512]
    const float* __restrict__ W1Tt,   // [16][512][128]
    const float* __restrict__ b1,     // [2048]
    unsigned short* __restrict__ spk) // bf16 [256][128][2048]
{
    const int hc  = blockIdx.x;   // 0..31, 64 h-cols each
    const int b   = blockIdx.y;
    const int tid = threadIdx.x;
    const int tx  = tid & 15;     // h micro-tile (cols tx*4..+3)
    const int ty  = tid >> 4;     // s micro-tile (rows ty*8..+7)

    // LDS: B stage [B0|B1] = 2 x 2048 floats (16 KB); scan buffer cur[128][72]
    // (36864 B) aliases the whole array.
    __shared__ float lds[9216];

    const float* xb   = x    + (size_t)b * 65536;
    const float* wt   = W1Tt + (size_t)(hc >> 1) * 65536;
    const int    hoff = (hc & 1) * 64;
    const float* arow = xb + (size_t)(ty * 8) * 512;   // this thread's 8 s-rows

    f32x2  acc2[8][2] = {};   // cols {2p, 2p+1}
    double accd[8][4] = {};

    auto stageB = [&](int p, int k0) {
        float* Bb = lds + p * 2048;   // [32 k][64 h] linear
#pragma unroll
        for (int it = 0; it < 2; ++it) {
            int t2 = tid + it * 256;                   // 0..511 granules
            int kk2 = t2 >> 4, c = (t2 & 15) << 2;     // 16 granules per k-row
            gload16(wt + (size_t)(k0 + kk2) * 128 + hoff + c, Bb + t2 * 4);
        }
    };

    auto computeTile = [&](int p, int k0) {
        const float* Bb = lds + p * 2048;
#pragma unroll
        for (int k4 = 0; k4 < 8; ++k4) {
            float4 av[8];
#pragma unroll
            for (int i = 0; i < 8; ++i)
                av[i] = *(const float4*)(arow + (size_t)i * 512 + k0 + k4 * 4);
#pragma unroll
            for (int kk = 0; kk < 4; ++kk) {
                const float4 c0 = *(const float4*)(Bb + (k4 * 4 + kk) * 64 + tx * 4);
                f32x2 b01, b23;
                b01[0] = c0.x; b01[1] = c0.y;
                b23[0] = c0.z; b23[1] = c0.w;
#pragma unroll
                for (int i = 0; i < 8; ++i) {
                    const float a = (kk == 0) ? av[i].x : (kk == 1) ? av[i].y
                                  : (kk == 2) ? av[i].z : av[i].w;
                    f32x2 aa; aa[0] = a; aa[1] = a;
                    acc2[i][0] = PKFMA(aa, b01, acc2[i][0]);
                    acc2[i][1] = PKFMA(aa, b23, acc2[i][1]);
                }
            }
        }
    };

    stageB(0, 0);
    __syncthreads();                       // prologue DMA drained
    for (int kt = 0; kt < 16; ++kt) {
        if (kt < 15) stageB((kt + 1) & 1, (kt + 1) * 32);   // prefetch next tile
        computeTile(kt & 1, kt * 32);
        // flush the 32-K fp32 chunk into the fp64 accumulator (every tile)
#pragma unroll
        for (int i = 0; i < 8; ++i) {
            accd[i][0] += (double)acc2[i][0][0]; acc2[i][0][0] = 0.f;
            accd[i][1] += (double)acc2[i][0][1]; acc2[i][0][1] = 0.f;
            accd[i][2] += (double)acc2[i][1][0]; acc2[i][1][0] = 0.f;
            accd[i][3] += (double)acc2[i][1][1]; acc2[i][1][1] = 0.f;
        }
        __syncthreads();                   // next-tile B-DMA complete
    }

    // dump tile to LDS (fp32) for the scan; stride 72 floats (288 B)
#pragma unroll
    for (int i = 0; i < 8; ++i) {
        const int r = ty * 8 + i;
        float4 v;
        v.x = (float)accd[i][0]; v.y = (float)accd[i][1];
        v.z = (float)accd[i][2]; v.w = (float)accd[i][3];
        *(float4*)(lds + r * 72 + tx * 4) = v;
    }
    __syncthreads();

    // LIF scan: one thread per h column (64), sequential over s, fp64 state
    if (tid < 64) {
        const float b1v = b1[hc * 64 + tid];
        double mem = 0.0;
        size_t base = ((size_t)b * 128) * 2048 + (size_t)hc * 64 + tid;
        for (int s = 0; s < 128; ++s) {
            float curf = lds[s * 72 + tid] + b1v;
            double reset = (mem > 1.0) ? 1.0 : 0.0;
            mem = 0.9 * mem + (double)curf - reset;   // THRESHOLD = 1
            spk[base + (size_t)s * 2048] = (mem > 1.0) ? (unsigned short)0x3F80u
                                                       : (unsigned short)0u;
        }
    }
}

// ---------- Kernel 2: W2 fp32 -> bf16 ----------
__global__ __launch_bounds__(256) void k_cvt(const float* __restrict__ W2,
                                             unsigned short* __restrict__ W2b)
{
    int i = blockIdx.x * 256 + threadIdx.x;   // 262144 float4s
    float4 v = ((const float4*)W2)[i];
    ushort4 o;
    o.x = f2bf(v.x); o.y = f2bf(v.y); o.z = f2bf(v.z); o.w = f2bf(v.w);
    ((ushort4*)W2b)[i] = o;
}

// ---------- Kernel 3: FC2 bf16 MFMA GEMM (128^2 tile, BK=32) ----------
__global__ __launch_bounds__(256) void k_fc2(
    const unsigned short* __restrict__ A,   // bf16 spikes [32768][2048]
    const unsigned short* __restrict__ B,   // bf16 W2 [512][2048]
    const float* __restrict__ b2,           // [512]
    float* __restrict__ out)                // [32768][512]
{
    __shared__ char ldsb[16384];
    char* As = ldsb;          // [128][32] bf16, row = 64 B
    char* Bs = ldsb + 8192;   // [128][32] bf16

    const int tid  = threadIdx.x;
    const int m0   = blockIdx.y * 128;
    const int n0   = blockIdx.x * 128;
    const int lane = tid & 63;
    const int wv   = tid >> 6;
    const int wm   = wv >> 1, wn = wv & 1;
    const int lr   = lane & 15;
    const int lk   = lane >> 4;

    f32x4 acc[4][4] = {};

    const char* gA = (const char*)(A + (size_t)m0 * 2048);
    const char* gB = (const char*)(B + (size_t)n0 * 2048);

    for (int kt = 0; kt < 64; ++kt) {
        const int kb = kt * 64;
        __syncthreads();
#pragma unroll
        for (int inst = 0; inst < 2; ++inst) {
            int o   = tid * 16 + inst * 4096;
            int row = o >> 6;
            int cb  = o & 63;
            gload16(gA + (size_t)row * 4096 + kb + cb, As + o);
            gload16(gB + (size_t)row * 4096 + kb + cb, Bs + o);
        }
        __syncthreads();

        short8 af[4], bf[4];
#pragma unroll
        for (int mi = 0; mi < 4; ++mi)
            af[mi] = *(const short8*)(As + (wm * 64 + mi * 16 + lr) * 64 + lk * 16);
#pragma unroll
        for (int ni = 0; ni < 4; ++ni)
            bf[ni] = *(const short8*)(Bs + (wn * 64 + ni * 16 + lr) * 64 + lk * 16);
#pragma unroll
        for (int mi = 0; mi < 4; ++mi)
#pragma unroll
            for (int ni = 0; ni < 4; ++ni)
                acc[mi][ni] = __builtin_amdgcn_mfma_f32_16x16x32_bf16(
                    af[mi], bf[ni], acc[mi][ni], 0, 0, 0);
    }

    float b2v[4];
#pragma unroll
    for (int ni = 0; ni < 4; ++ni) b2v[ni] = b2[n0 + wn * 64 + ni * 16 + lr];

#pragma unroll
    for (int mi = 0; mi < 4; ++mi) {
        const int rb = m0 + wm * 64 + mi * 16 + lk * 4;
#pragma unroll
        for (int ni = 0; ni < 4; ++ni) {
            const int c = n0 + wn * 64 + ni * 16 + lr;
#pragma unroll
            for (int r = 0; r < 4; ++r)
                out[(size_t)(rb + r) * 512 + c] = acc[mi][ni][r] + b2v[ni];
        }
    }
}

// ---------- launch ----------
extern "C" void kernel_launch(void* const* d_in, const int* in_sizes, int n_in,
                              void* d_out, int out_size, void* d_ws, size_t ws_size,
                              hipStream_t stream) {
    const float* x  = (const float*)d_in[0];   // [256][128][512]
    const float* W1 = (const float*)d_in[1];   // [2048][512]
    const float* b1 = (const float*)d_in[2];   // [2048]
    const float* W2 = (const float*)d_in[3];   // [512][2048]
    const float* b2 = (const float*)d_in[4];   // [512]
    float* out = (float*)d_out;                // [256][128][512]

    unsigned short* spk  = (unsigned short*)d_ws;                       // 128 MiB
    unsigned short* W2b  = (unsigned short*)((char*)d_ws + 134217728);  // 2 MiB
    float*          W1Tt = (float*)((char*)d_ws + 136314880);           // 4 MiB

    k_tw      <<<dim3(16, 4, 16), 256, 0, stream>>>(W1, W1Tt);
    k_fc1_scan<<<dim3(32, 256),   256, 0, stream>>>(x, W1Tt, b1, spk);
    k_cvt     <<<dim3(1024),      256, 0, stream>>>(W2, W2b);
    k_fc2     <<<dim3(4, 256),    256, 0, stream>>>(spk, W2b, b2, out);
}

// Round 13
// 1071.546 us; speedup vs baseline: 1.2757x; 1.2757x over previous
//
#include <hip/hip_runtime.h>

// ---------- helpers ----------
typedef __attribute__((ext_vector_type(8))) short short8;
typedef __attribute__((ext_vector_type(4))) float f32x4;

__device__ __forceinline__ unsigned short f2bf(float f) {
    unsigned int u = __float_as_uint(f);
    unsigned int r = (u + 0x7FFFu + ((u >> 16) & 1u)) >> 16;   // RNE
    return (unsigned short)r;
}

__device__ __forceinline__ void gload16(const void* g, void* l) {
    __builtin_amdgcn_global_load_lds(
        (const __attribute__((address_space(1))) unsigned int*)g,
        (__attribute__((address_space(3))) unsigned int*)l,
        16, 0, 0);
}

// ---------- Kernel 0: W1[2048][512] -> W1Tt[hc][512][128] (per-hc k-major tiles)
__global__ __launch_bounds__(256) void k_tw(const float* __restrict__ W1,
                                            float* __restrict__ W1Tt) {
    const int tx = threadIdx.x & 31, ty = threadIdx.x >> 5;   // 32 x 8
    const int k0 = blockIdx.x * 32, j0 = blockIdx.y * 32, hc = blockIdx.z;
    __shared__ float t[32][33];
#pragma unroll
    for (int i = 0; i < 4; ++i)
        t[ty + i * 8][tx] = W1[(size_t)(hc * 128 + j0 + ty + i * 8) * 512 + k0 + tx];
    __syncthreads();
#pragma unroll
    for (int i = 0; i < 4; ++i)
        W1Tt[(size_t)hc * 65536 + (size_t)(k0 + ty + i * 8) * 128 + j0 + tx] =
            t[tx][ty + i * 8];
}

// ---------- Kernel 1: fused FC1 (fp32 GEMM, fp64-chunk accum) + LIF scan ----------
// grid (32 h-chunks of 64, 256 batches), 256 threads. Tile 128s x 64h, K=512,
// BK=32, round-10 compute loop verbatim (A LDS-staged + XOR swizzle, B LDS).
// Round-12 change: SINGLE-buffered stage (24 KB) + unpadded scan buffer
// (128x64 = 32 KB alias) -> LDS_Block_Size 32768 -> 4-5 blocks/CU (was 49152
// -> 2). Double-buffering was dead weight: the vmcnt(0) drain before each
// barrier waits for the prefetch too (round-9: barrier count change = 0 gain);
// occupancy is the lever that worked (round 9->10: 1->2 blocks, -400us).
// Numerics bitwise-identical: k ascends kt->k4->kk, fp64 flush every 32 k.
// No min-waves launch_bounds (round-2 spill lesson).
__global__ __launch_bounds__(256) void k_fc1_scan(
    const float* __restrict__ x,      // [256][128][512]
    const float* __restrict__ W1Tt,   // [16][512][128]
    const float* __restrict__ b1,     // [2048]
    unsigned short* __restrict__ spk) // bf16 [256][128][2048]
{
    const int hc  = blockIdx.x;   // 0..31, 64 h-cols each
    const int b   = blockIdx.y;
    const int tid = threadIdx.x;
    const int tx  = tid & 15;     // h micro-tile (cols tx*4..+3)
    const int ty  = tid >> 4;     // s micro-tile (rows ty*8..+7)

    // LDS: stage A[128][32] (4096 f) + B[32][64] (2048 f) = 24 KB, aliased by
    // scan buffer cur[128][64] (8192 f = 32 KB). Total block LDS = 32768 B.
    __shared__ float lds[8192];

    const float* xb   = x    + (size_t)b * 65536;
    const float* wt   = W1Tt + (size_t)(hc >> 1) * 65536;
    const int    hoff = (hc & 1) * 64;

    float  acc[8][4]  = {};
    double accd[8][4] = {};

    float* Ab = lds;          // [128 s][32 k], granule-XOR swizzled by row ty
    float* Bb = lds + 4096;   // [32 k][64 h] linear

    auto stage = [&](int k0) {
#pragma unroll
        for (int it = 0; it < 4; ++it) {
            int t = tid + it * 256;                    // 0..1023 A-granules
            int row = t >> 3, g = t & 7;
            gload16(xb + (size_t)row * 512 + k0 + ((g ^ ((row >> 3) & 7)) << 2),
                    Ab + t * 4);
        }
#pragma unroll
        for (int it = 0; it < 2; ++it) {
            int t2 = tid + it * 256;                   // 0..511 B-granules
            int kk2 = t2 >> 4, c = (t2 & 15) << 2;     // 16 granules per k-row
            gload16(wt + (size_t)(k0 + kk2) * 128 + hoff + c, Bb + t2 * 4);
        }
    };

    auto computeTile = [&]() {
#pragma unroll
        for (int k4 = 0; k4 < 8; ++k4) {
            float4 av[8];
#pragma unroll
            for (int i = 0; i < 8; ++i)
                av[i] = *(const float4*)(Ab + (ty * 8 + i) * 32 +
                                         ((k4 ^ (ty & 7)) << 2));
#pragma unroll
            for (int kk = 0; kk < 4; ++kk) {
                const float4 c0 = *(const float4*)(Bb + (k4 * 4 + kk) * 64 + tx * 4);
#pragma unroll
                for (int i = 0; i < 8; ++i) {
                    const float a = (kk == 0) ? av[i].x : (kk == 1) ? av[i].y
                                  : (kk == 2) ? av[i].z : av[i].w;
                    acc[i][0] = fmaf(a, c0.x, acc[i][0]);
                    acc[i][1] = fmaf(a, c0.y, acc[i][1]);
                    acc[i][2] = fmaf(a, c0.z, acc[i][2]);
                    acc[i][3] = fmaf(a, c0.w, acc[i][3]);
                }
            }
        }
    };

    for (int kt = 0; kt < 16; ++kt) {
        if (kt) __syncthreads();           // prior tile's compute done, LDS free
        stage(kt * 32);
        __syncthreads();                   // vmcnt(0): DMA complete
        computeTile();
        // flush the 32-K fp32 chunk into the fp64 accumulator (every tile)
#pragma unroll
        for (int i = 0; i < 8; ++i)
#pragma unroll
            for (int j = 0; j < 4; ++j) {
                accd[i][j] += (double)acc[i][j];
                acc[i][j] = 0.f;
            }
    }

    __syncthreads();                       // compute done before scan-alias write
    // dump tile to LDS (fp32) for the scan; stride 64 floats (256 B)
#pragma unroll
    for (int i = 0; i < 8; ++i) {
        const int r = ty * 8 + i;
        float4 v;
        v.x = (float)accd[i][0]; v.y = (float)accd[i][1];
        v.z = (float)accd[i][2]; v.w = (float)accd[i][3];
        *(float4*)(lds + r * 64 + tx * 4) = v;
    }
    __syncthreads();

    // LIF scan: one thread per h column (64), sequential over s, fp64 state
    if (tid < 64) {
        const float b1v = b1[hc * 64 + tid];
        double mem = 0.0;
        size_t base = ((size_t)b * 128) * 2048 + (size_t)hc * 64 + tid;
        for (int s = 0; s < 128; ++s) {
            float curf = lds[s * 64 + tid] + b1v;
            double reset = (mem > 1.0) ? 1.0 : 0.0;
            mem = 0.9 * mem + (double)curf - reset;   // THRESHOLD = 1
            spk[base + (size_t)s * 2048] = (mem > 1.0) ? (unsigned short)0x3F80u
                                                       : (unsigned short)0u;
        }
    }
}

// ---------- Kernel 2: W2 fp32 -> bf16 ----------
__global__ __launch_bounds__(256) void k_cvt(const float* __restrict__ W2,
                                             unsigned short* __restrict__ W2b)
{
    int i = blockIdx.x * 256 + threadIdx.x;   // 262144 float4s
    float4 v = ((const float4*)W2)[i];
    ushort4 o;
    o.x = f2bf(v.x); o.y = f2bf(v.y); o.z = f2bf(v.z); o.w = f2bf(v.w);
    ((ushort4*)W2b)[i] = o;
}

// ---------- Kernel 3: FC2 bf16 MFMA GEMM (128^2 tile, BK=32) ----------
__global__ __launch_bounds__(256) void k_fc2(
    const unsigned short* __restrict__ A,   // bf16 spikes [32768][2048]
    const unsigned short* __restrict__ B,   // bf16 W2 [512][2048]
    const float* __restrict__ b2,           // [512]
    float* __restrict__ out)                // [32768][512]
{
    __shared__ char ldsb[16384];
    char* As = ldsb;          // [128][32] bf16, row = 64 B
    char* Bs = ldsb + 8192;   // [128][32] bf16

    const int tid  = threadIdx.x;
    const int m0   = blockIdx.y * 128;
    const int n0   = blockIdx.x * 128;
    const int lane = tid & 63;
    const int wv   = tid >> 6;
    const int wm   = wv >> 1, wn = wv & 1;
    const int lr   = lane & 15;
    const int lk   = lane >> 4;

    f32x4 acc[4][4] = {};

    const char* gA = (const char*)(A + (size_t)m0 * 2048);
    const char* gB = (const char*)(B + (size_t)n0 * 2048);

    for (int kt = 0; kt < 64; ++kt) {
        const int kb = kt * 64;
        __syncthreads();
#pragma unroll
        for (int inst = 0; inst < 2; ++inst) {
            int o   = tid * 16 + inst * 4096;
            int row = o >> 6;
            int cb  = o & 63;
            gload16(gA + (size_t)row * 4096 + kb + cb, As + o);
            gload16(gB + (size_t)row * 4096 + kb + cb, Bs + o);
        }
        __syncthreads();

        short8 af[4], bf[4];
#pragma unroll
        for (int mi = 0; mi < 4; ++mi)
            af[mi] = *(const short8*)(As + (wm * 64 + mi * 16 + lr) * 64 + lk * 16);
#pragma unroll
        for (int ni = 0; ni < 4; ++ni)
            bf[ni] = *(const short8*)(Bs + (wn * 64 + ni * 16 + lr) * 64 + lk * 16);
#pragma unroll
        for (int mi = 0; mi < 4; ++mi)
#pragma unroll
            for (int ni = 0; ni < 4; ++ni)
                acc[mi][ni] = __builtin_amdgcn_mfma_f32_16x16x32_bf16(
                    af[mi], bf[ni], acc[mi][ni], 0, 0, 0);
    }

    float b2v[4];
#pragma unroll
    for (int ni = 0; ni < 4; ++ni) b2v[ni] = b2[n0 + wn * 64 + ni * 16 + lr];

#pragma unroll
    for (int mi = 0; mi < 4; ++mi) {
        const int rb = m0 + wm * 64 + mi * 16 + lk * 4;
#pragma unroll
        for (int ni = 0; ni < 4; ++ni) {
            const int c = n0 + wn * 64 + ni * 16 + lr;
#pragma unroll
            for (int r = 0; r < 4; ++r)
                out[(size_t)(rb + r) * 512 + c] = acc[mi][ni][r] + b2v[ni];
        }
    }
}

// ---------- launch ----------
extern "C" void kernel_launch(void* const* d_in, const int* in_sizes, int n_in,
                              void* d_out, int out_size, void* d_ws, size_t ws_size,
                              hipStream_t stream) {
    const float* x  = (const float*)d_in[0];   // [256][128][512]
    const float* W1 = (const float*)d_in[1];   // [2048][512]
    const float* b1 = (const float*)d_in[2];   // [2048]
    const float* W2 = (const float*)d_in[3];   // [512][2048]
    const float* b2 = (const float*)d_in[4];   // [512]
    float* out = (float*)d_out;                // [256][128][512]

    unsigned short* spk  = (unsigned short*)d_ws;                       // 128 MiB
    unsigned short* W2b  = (unsigned short*)((char*)d_ws + 134217728);  // 2 MiB
    float*          W1Tt = (float*)((char*)d_ws + 136314880);           // 4 MiB

    k_tw      <<<dim3(16, 4, 16), 256, 0, stream>>>(W1, W1Tt);
    k_fc1_scan<<<dim3(32, 256),   256, 0, stream>>>(x, W1Tt, b1, spk);
    k_cvt     <<<dim3(1024),      256, 0, stream>>>(W2, W2b);
    k_fc2     <<<dim3(4, 256),    256, 0, stream>>>(spk, W2b, b2, out);
}